// Round 21
// baseline (141.368 us; speedup 1.0000x reference)
//
#include <hip/hip_runtime.h>
#include <hip/hip_fp16.h>

// BaggingMaxPool: out[d] = mean_k( max_{r in indices[k,:]} inp[r][d] )
// N=1024 rows, D=100000 cols, K=20 rounds, SELECT_N=256.
//
// Round-21 = Round-20 + ONE change: NON-TEMPORAL input loads.
// Ledger r1-r20: every structure (gather-LDS, dense-reg, producer/consumer,
// async gload_lds) pins at 115-145us while compute models at <=55us. The
// constant: 410MB delivered at ~3.6 TB/s effective (200MB HBM FETCH + 210MB
// via L3). Hypothesis: the L3-serving path caps delivery (~2-3 TB/s), not
// HBM. __builtin_nontemporal_load (nt) streams inp from HBM bypassing
// cache allocation -> 410MB at ~6.3TB/s ~ 65us.
// Signature to check: select FETCH_SIZE 200MB -> ~410MB.
// Rest identical to R20: 3-VALU/round/2-col select (sbfe+bfi+pk_max),
// f16x2 acc[20] (20 VGPR), A/B 8-row prefetch, RS=4 row-splits, 16MB ws
// partials, mask kernel -> out[0..1023] scratch, combine kernel.

#define D_COLS  100000
#define NPAIR   50000                   // f16x2 column pairs
#define N_ROWS  1024
#define KR      20
#define NIDX    (KR * 256)              // 5120
#define RS      4                       // row splits
#define RPS     (N_ROWS / RS)           // 256 rows per split
#define BLOCK   256
#define NCB     ((NPAIR + BLOCK - 1) / BLOCK)   // 196
#define NINF2   0xFC00FC00u             // (-inf, -inf) f16x2

typedef __fp16 f16x2_t __attribute__((ext_vector_type(2)));

__device__ __forceinline__ unsigned cvt_pk(float x, float y) {
    union { f16x2_t h; unsigned u; } c;
    c.h = __builtin_amdgcn_cvt_pkrtz(x, y);
    return c.u;
}

// ---- kernel 0: per-row 20-bit round-membership masks -> out[0..1023] ----
__global__ __launch_bounds__(1024) void mask_kernel(
    const int* __restrict__ idx, unsigned* __restrict__ maskbuf)
{
    __shared__ unsigned sm[N_ROWS];
    const int tid = threadIdx.x;        // 1024 threads == N_ROWS
    sm[tid] = 0u;
    __syncthreads();
    for (int i = tid; i < NIDX; i += 1024)
        atomicOr(&sm[idx[i]], 1u << (i >> 8));
    __syncthreads();
    maskbuf[tid] = sm[tid];
}

// ---- kernel 1: dense select-max over this split's 256 rows ----
__device__ __forceinline__ void loadc(float2 (&X)[8], const float* __restrict__ p, int grow0) {
    #pragma unroll
    for (int j = 0; j < 8; ++j) {
        // non-temporal: stream from HBM, skip L3 allocate (the delivery-cap fix)
        const unsigned long long v = __builtin_nontemporal_load(
            reinterpret_cast<const unsigned long long*>(p + (size_t)(grow0 + j) * D_COLS));
        union { unsigned long long u; float2 f; } c; c.u = v;
        X[j] = c.f;
    }
}

__device__ __forceinline__ void proc8(const float2 (&X)[8], const unsigned* lm, int base,
                                      unsigned ninf, unsigned (&acc)[KR]) {
    #pragma unroll
    for (int j = 0; j < 8; ++j) {
        const unsigned mv = lm[base + j];                 // LDS broadcast -> VGPR
        const unsigned vu = cvt_pk(X[j].x, X[j].y);
        #pragma unroll
        for (int k = 0; k < KR; ++k) {
            const int b = __builtin_amdgcn_sbfe((int)mv, k, 1);   // 0 / -1
            unsigned sel;
            asm("v_bfi_b32 %0, %1, %2, %3" : "=v"(sel) : "v"(b), "v"(vu), "s"(ninf));
            asm("v_pk_max_f16 %0, %0, %1" : "+v"(acc[k]) : "v"(sel));
        }
    }
}

__global__ __launch_bounds__(BLOCK, 4) void select_kernel(
    const float* __restrict__ inp,
    const unsigned* __restrict__ maskbuf,
    unsigned* __restrict__ parts)          // [RS][KR][NPAIR] u32 (f16x2)
{
    __shared__ unsigned lm[RPS];
    const int tid = threadIdx.x;
    const int s   = blockIdx.y;

    lm[tid] = maskbuf[s * RPS + tid];      // BLOCK == RPS == 256
    __syncthreads();

    const int pi  = blockIdx.x * BLOCK + tid;
    const int pic = pi < NPAIR ? pi : NPAIR - 1;        // clamp loads, guard store
    const float* p = inp + (size_t)pic * 2;
    const int r0 = s * RPS;
    const unsigned ninf = NINF2;

    unsigned acc[KR];
    #pragma unroll
    for (int k = 0; k < KR; ++k) acc[k] = NINF2;

    float2 A[8], B[8];
    loadc(A, p, r0);
    #pragma unroll 1
    for (int c = 0; c < RPS; c += 16) {
        loadc(B, p, r0 + c + 8);
        proc8(A, lm, c, ninf, acc);
        const int nb = (c + 16 < RPS) ? (c + 16) : (RPS - 8);   // dead reload on last iter
        loadc(A, p, r0 + nb);
        proc8(B, lm, c + 8, ninf, acc);
    }

    if (pi < NPAIR) {
        #pragma unroll
        for (int k = 0; k < KR; ++k)
            parts[((size_t)(s * KR + k)) * NPAIR + pi] = acc[k];
    }
}

// ---- kernel 2: pk_max across splits, unpack, mean, write f32 ----
__global__ __launch_bounds__(BLOCK) void combine_kernel(
    const unsigned* __restrict__ parts, float* __restrict__ out)
{
    const int pi = blockIdx.x * BLOCK + threadIdx.x;
    if (pi >= NPAIR) return;

    float sx = 0.f, sy = 0.f;
    #pragma unroll
    for (int k = 0; k < KR; ++k) {
        unsigned m = NINF2;
        #pragma unroll
        for (int s = 0; s < RS; ++s) {
            const unsigned v = parts[((size_t)(s * KR + k)) * NPAIR + pi];
            asm("v_pk_max_f16 %0, %0, %1" : "+v"(m) : "v"(v));
        }
        const __half2 h = *reinterpret_cast<const __half2*>(&m);
        const float2 f = __half22float2(h);
        sx += f.x; sy += f.y;
    }
    *reinterpret_cast<float2*>(out + 2 * pi) =
        make_float2(sx * (1.0f / KR), sy * (1.0f / KR));
}

extern "C" void kernel_launch(void* const* d_in, const int* in_sizes, int n_in,
                              void* d_out, int out_size, void* d_ws, size_t ws_size,
                              hipStream_t stream) {
    const float* inp     = (const float*)d_in[0];
    const int*   indices = (const int*)d_in[1];
    float*       out     = (float*)d_out;
    unsigned*    maskbuf = (unsigned*)d_out;   // out[0..1023] as mask scratch;
                                               // combine_kernel overwrites all of out
    unsigned*    parts   = (unsigned*)d_ws;    // RS*KR*NPAIR*4 = 16,000,000 B

    mask_kernel<<<1, 1024, 0, stream>>>(indices, maskbuf);
    dim3 g1(NCB, RS);
    select_kernel<<<g1, BLOCK, 0, stream>>>(inp, maskbuf, parts);
    combine_kernel<<<NCB, BLOCK, 0, stream>>>(parts, out);
}